// Round 12
// baseline (2915.247 us; speedup 1.0000x reference)
//
#include <hip/hip_runtime.h>

// VaeRNNDecoder: 512-step LSTM with output feedback, B=256, H=512.
// Folded recurrence: gates_t = h_t @ W_eff^T + b_eff,  W_eff = W_ih@W_last + W_hh.
// ROUND 12: r11 geometry (16 groups x 16 batches x 16 pair-blocks, full chip)
// with the rendezvous ELIMINATED: h is broadcast as 32-bit words [h:16|seq:16]
// (one dword store = single-copy atomic -> reader sees h+seq together).
// Consumers load the parity buffer and retry chunks whose seq != t. This
// collapses {store-drain, counter publish, detect spin, wake} (~2+ LLC RTTs
// + 2 syncthreads per step) into the stage load itself. Double buffering by
// parity kept: seeing all seq==t proves every block finished reading the
// buffer being overwritten with t+1 (transitive safety as before).
// Anti-hoist (rule 18): the waitcnt asm takes the loaded regs as "+v" so the
// seq check is SSA-ordered after the wait.
// Ledger: r1/r2 sc0-only BROKEN. r3 wide POLL loops flood LLC (this is not a
// poll: only stale DATA chunks re-read, bounded). r4=1755. r5/r6 tick
// pipeline 2x worse. r7 bundling. r8 flag-line 1877. r9 atomic-swap 1814
// (write-through theory false). r10 bfrag[5] spills (budget 3 tiles).
// r11 full chip +1.6% only -> step is rendezvous-RTT-bound, hence this.

#define HH 512
#define TT 512

typedef _Float16 half8 __attribute__((ext_vector_type(8)));
typedef float f32x4 __attribute__((ext_vector_type(4)));
typedef unsigned int u32x2 __attribute__((ext_vector_type(2)));
typedef unsigned int u32x4 __attribute__((ext_vector_type(4)));

__device__ __forceinline__ float sigm(float x) { return 1.0f / (1.0f + __expf(-x)); }
__device__ __forceinline__ float tanh_(float x) { return 1.0f - 2.0f / (__expf(2.0f * x) + 1.0f); }
__device__ __forceinline__ unsigned short f16b(float x) {
    _Float16 h = (_Float16)x;
    return __builtin_bit_cast(unsigned short, h);
}

// ---------------- K1: W_eff gate rows -> Wbig (packed, f16) ----------------
__global__ __launch_bounds__(256) void k_weff(const float* __restrict__ Wih,
                                              const float* __restrict__ Whh,
                                              const float* __restrict__ Wlast,
                                              unsigned short* __restrict__ Wbig) {
    __shared__ float wih[16 * 512];
    const int tid = threadIdx.x;
    const int r0 = blockIdx.x * 16;
    for (int i = tid; i < (16 * 512) / 4; i += 256) {
        ((float4*)wih)[i] = ((const float4*)(Wih + (size_t)r0 * 512))[i];
    }
    __syncthreads();
    float acc0[16], acc1[16];
#pragma unroll
    for (int rr = 0; rr < 16; ++rr) { acc0[rr] = 0.f; acc1[rr] = 0.f; }
    const int k0 = tid * 2;
    for (int j = 0; j < 512; ++j) {
        const float2 wl = *(const float2*)(Wlast + (size_t)j * 512 + k0);
#pragma unroll
        for (int rr = 0; rr < 16; ++rr) {
            const float a = wih[rr * 512 + j];
            acc0[rr] += a * wl.x;
            acc1[rr] += a * wl.y;
        }
    }
#pragma unroll
    for (int rr = 0; rr < 16; ++rr) {
        const int gr = r0 + rr;
        const int q = gr >> 9, j = gr & 511;
        const int dst = 80 * (j >> 4) + q * 16 + (j & 15);
        const float v0 = acc0[rr] + Whh[(size_t)gr * 512 + k0];
        const float v1 = acc1[rr] + Whh[(size_t)gr * 512 + k0 + 1];
        Wbig[(size_t)dst * 512 + k0] = f16b(v0);
        Wbig[(size_t)dst * 512 + k0 + 1] = f16b(v1);
    }
}

// ---------------- K2: pack W0big, y-rows, biases, hbuf32 init ------
__global__ __launch_bounds__(256) void k_pack(const float* __restrict__ z,
                                              const float* __restrict__ Wih,
                                              const float* __restrict__ Whh,
                                              const float* __restrict__ bih,
                                              const float* __restrict__ bhh,
                                              const float* __restrict__ Wlast,
                                              const float* __restrict__ blast,
                                              unsigned short* __restrict__ Wbig,
                                              unsigned short* __restrict__ W0big,
                                              float* __restrict__ biasEff,
                                              float* __restrict__ bias0,
                                              unsigned int* __restrict__ hbuf32) {
    const int nthr = gridDim.x * blockDim.x;
    const int gtid = blockIdx.x * blockDim.x + threadIdx.x;
    for (int e = gtid; e < 2560 * 512; e += nthr) {
        const int r = e >> 9, k = e & 511;
        const int s = r / 80, rem = r - s * 80;
        const int tau = rem >> 4, jj = rem & 15;
        const int j = s * 16 + jj;
        if (tau == 4) {
            const unsigned short v = f16b(Wlast[(size_t)j * 512 + k]);
            Wbig[e] = v;
            W0big[e] = v;
        } else {
            const int gr = tau * 512 + j;
            W0big[e] = f16b(Wih[(size_t)gr * 512 + k] + Whh[(size_t)gr * 512 + k]);
        }
    }
    for (int r = gtid; r < 2560; r += nthr) {
        const int s = r / 80, rem = r - s * 80;
        const int tau = rem >> 4, jj = rem & 15;
        const int j = s * 16 + jj;
        if (tau == 4) {
            bias0[r] = blast[j];
            biasEff[r] = blast[j];
        } else {
            const int gr = tau * 512 + j;
            const float base = bih[gr] + bhh[gr];
            float dot = 0.f;
            for (int k = 0; k < 512; ++k) dot += Wih[(size_t)gr * 512 + k] * blast[k];
            bias0[r] = base;
            biasEff[r] = base + dot;
        }
    }
    // hbuf32: [g(16)][parity(2)][16 batch][512 col] u32 = [h:16|seq:16].
    // parity0 seeded with z tagged seq=0; parity1 poisoned (seq=0xFFFF).
    for (int e = gtid; e < 256 * 512; e += nthr) {
        const int b = e >> 9, k = e & 511;
        const int g = b >> 4, bl = b & 15;
        unsigned int* base = hbuf32 + (size_t)g * 16384 + bl * 512 + k;
        base[0] = ((unsigned int)f16b(z[e]) << 16);  // seq = 0
        base[8192] = 0xFFFFFFFFu;
    }
}

// ---------------- K3: persistent recurrence, rendezvous-free ----------------
// 256 blocks = 16 groups (blockIdx&15, 16 batches each) x 16 pairs
// (blockIdx>>4). Pair-block owns hidden cols [32*pair, 32*pair+32) = slices
// {2p,2p+1} = 160 packed rows. Waves: w0 slA{i,f,g}; w1 slA{o,y};
// w2 slB{i,f,g}; w3 slB{o,y}; one 16-batch M-tile.
__global__ __launch_bounds__(256, 1) void k_lstm(const unsigned short* __restrict__ Wbig,
                                                 const unsigned short* __restrict__ W0big,
                                                 const float* __restrict__ biasEff,
                                                 const float* __restrict__ bias0,
                                                 unsigned int* __restrict__ hbuf32,
                                                 const float* __restrict__ z,
                                                 float* __restrict__ out) {
    const int g = blockIdx.x & 15;
    const int pair = blockIdx.x >> 4;
    const int tid = threadIdx.x;
    const int wave = tid >> 6;
    const int lane = tid & 63;
    const int l15 = lane & 15;
    const int q4 = lane >> 4;

    __shared__ unsigned short hstage[16 * 520];  // 16 batches x 512 cols f16, stride 520
    __shared__ float gatesL[2 * 16 * 68];        // [sl][b][i(16) f g o], stride 68
    __shared__ float cL[2 * 16 * 18];            // [sl][b][16 cells], stride 18

    const int sl = wave >> 1;
    const int slice = 2 * pair + sl;
    const int ntile0 = (wave & 1) ? 3 : 0;
    const int ntcount = (wave & 1) ? 2 : 3;

    unsigned int* hbg = hbuf32 + (size_t)g * 16384;  // [parity 8192 words][16][512]

    // c init from z (fp32 exact): 512 cells (16 batches x 32 cols), 2/thread
    for (int idx = tid; idx < 512; idx += 256) {
        const int b = idx >> 5, j0 = idx & 31;
        const int s2 = j0 >> 4, jj = j0 & 15;
        cL[(s2 * 16 + b) * 18 + jj] = z[(size_t)(g * 16 + b) * 512 + 32 * pair + j0];
    }

    // persistent B-fragments (fp16 weights), start with W0
    half8 bfrag[3][16];
#pragma unroll
    for (int tt = 0; tt < 3; ++tt) {
        if (tt < ntcount) {
            const int row = 80 * slice + (ntile0 + tt) * 16 + l15;
#pragma unroll
            for (int kk = 0; kk < 16; ++kk) {
                bfrag[tt][kk] = *(const half8*)(W0big + (size_t)row * 512 + kk * 32 + q4 * 8);
            }
        }
    }
    float bias0v[3], biasEv[3];
#pragma unroll
    for (int tt = 0; tt < 3; ++tt) {
        if (tt < ntcount) {
            const int r = 80 * slice + (ntile0 + tt) * 16 + l15;
            bias0v[tt] = bias0[r];
            biasEv[tt] = biasEff[r];
        } else {
            bias0v[tt] = 0.f;
            biasEv[tt] = 0.f;
        }
    }

    for (int t = 0; t <= 512; ++t) {
        // ---- stage h(t): seq-validated loads, retry stale chunks ----
        // 32KB/block: 8 chunks x 16B/thread. A chunk is valid when its 4 seq
        // fields == t. No rendezvous: validity is carried by the data.
        {
            const unsigned int seqt = (unsigned int)t;
            unsigned int* bufp = hbg + ((t & 1) ? 8192 : 0);
            u32x4 st[8];
            bool valid[8] = {false, false, false, false, false, false, false, false};
            int pass = 0;
            while (true) {
#pragma unroll
                for (int i = 0; i < 8; ++i) {
                    if (!valid[i]) {
                        const char* p = (const char*)bufp + (i * 256 + tid) * 16;
                        asm volatile("global_load_dwordx4 %0, %1, off sc0 sc1"
                                     : "=&v"(st[i])
                                     : "v"(p)
                                     : "memory");
                    }
                }
                // "+v" outputs: seq checks below are SSA-ordered AFTER the wait
                // (rule 18: a bare waitcnt asm does not order register reads).
                asm volatile("s_waitcnt vmcnt(0)"
                             : "+v"(st[0]), "+v"(st[1]), "+v"(st[2]), "+v"(st[3]),
                               "+v"(st[4]), "+v"(st[5]), "+v"(st[6]), "+v"(st[7])
                             :
                             : "memory");
                bool all = true;
#pragma unroll
                for (int i = 0; i < 8; ++i) {
                    if (!valid[i]) {
                        valid[i] = ((st[i][0] & 0xFFFFu) == seqt) & ((st[i][1] & 0xFFFFu) == seqt) &
                                   ((st[i][2] & 0xFFFFu) == seqt) & ((st[i][3] & 0xFFFFu) == seqt);
                    }
                    all = all & valid[i];
                }
                if (__ballot(!all) == 0ull) break;
                if (++pass >= 8192) break;  // protocol bug -> wrong answer, not hang
            }
            // unpack high halves -> packed f16 -> LDS (8B writes, stride-8B: conflict-free)
#pragma unroll
            for (int i = 0; i < 8; ++i) {
                const int ci = i * 256 + tid;      // 16B chunk = 4 cols
                const int row = ci >> 7;           // batch 0..15
                const int colw = (ci & 127) * 4;   // col base
                u32x2 pk;
                pk.x = (st[i][0] >> 16) | (st[i][1] & 0xFFFF0000u);
                pk.y = (st[i][2] >> 16) | (st[i][3] & 0xFFFF0000u);
                *(u32x2*)(hstage + row * 520 + colw) = pk;
            }
        }
        __syncthreads();

        // ---- MFMA: [gates | y] = h @ Wbig_pair^T + bias, one M-tile ----
        f32x4 acc[3];
#pragma unroll
        for (int tt = 0; tt < 3; ++tt) {
            const float bv = (t == 0) ? bias0v[tt] : biasEv[tt];
            acc[tt] = (f32x4){bv, bv, bv, bv};
        }
#pragma unroll
        for (int kk = 0; kk < 16; ++kk) {
            const half8 a = *(const half8*)(hstage + l15 * 520 + kk * 32 + q4 * 8);
#pragma unroll
            for (int tt = 0; tt < 3; ++tt) {
                if (tt < ntcount)
                    acc[tt] = __builtin_amdgcn_mfma_f32_16x16x32_f16(a, bfrag[tt][kk], acc[tt], 0, 0, 0);
            }
        }

        // ---- y_{t-1} output (waves 1/3 hold the y tile in acc[1]) ----
        // Plain HBM stores; their ack hides under the next stage's load RTT.
        if ((wave & 1) && t >= 1) {
            const int n = 16 * slice + l15;
#pragma unroll
            for (int r = 0; r < 4; ++r) {
                const int m = q4 * 4 + r;
                const size_t off = (size_t)(g * 16 + m) * (TT * HH) + (size_t)(t - 1) * HH + n;
                out[off] = acc[1][r];
            }
        }
        if (t == 512) break;

        // ---- gate tiles -> LDS ----
        {
            const int nst = (wave & 1) ? 1 : 3;
#pragma unroll
            for (int tt = 0; tt < 3; ++tt) {
                if (tt < nst) {
                    const int col = (ntile0 + tt) * 16 + l15;
#pragma unroll
                    for (int r = 0; r < 4; ++r) {
                        const int m = q4 * 4 + r;
                        gatesL[(sl * 16 + m) * 68 + col] = acc[tt][r];
                    }
                }
            }
        }
        __syncthreads();

        // ---- cell update: 2 cells/thread; publish h(t+1) tagged seq=t+1 ----
        // No drain, no counter, no spin, no wake: consumers' seq checks do it.
        {
            const int b = tid >> 4, jp = tid & 15;
            const int j0 = jp * 2;
            const int s2 = j0 >> 4, jj = j0 & 15;
            const float* gb = gatesL + (s2 * 16 + b) * 68;
            const float2 iv = *(const float2*)(gb + jj);
            const float2 fvv = *(const float2*)(gb + 16 + jj);
            const float2 gv = *(const float2*)(gb + 32 + jj);
            const float2 ov = *(const float2*)(gb + 48 + jj);
            float* cp = cL + (s2 * 16 + b) * 18 + jj;
            float2 cv = *(const float2*)cp;
            const float c0 = sigm(fvv.x) * cv.x + sigm(iv.x) * tanh_(gv.x);
            const float c1 = sigm(fvv.y) * cv.y + sigm(iv.y) * tanh_(gv.y);
            const float h0 = sigm(ov.x) * tanh_(c0);
            const float h1 = sigm(ov.y) * tanh_(c1);
            cv.x = c0;
            cv.y = c1;
            *(float2*)cp = cv;
            const unsigned int seq1 = (unsigned int)(t + 1);
            unsigned int* dstp =
                hbg + (((t + 1) & 1) ? 8192 : 0) + b * 512 + 32 * pair + j0;
            u32x2 w2;
            w2.x = ((unsigned int)f16b(h0) << 16) | seq1;
            w2.y = ((unsigned int)f16b(h1) << 16) | seq1;
            asm volatile("global_store_dwordx2 %0, %1, off sc0 sc1" ::"v"(dstp), "v"(w2)
                         : "memory");
        }

        // after step 0, swap persistent weights W0 -> W_eff; register deps
        // order these loads before their first MFMA use automatically.
        if (t == 0) {
#pragma unroll
            for (int tt = 0; tt < 3; ++tt) {
                if (tt < ntcount) {
                    const int row = 80 * slice + (ntile0 + tt) * 16 + l15;
#pragma unroll
                    for (int kk = 0; kk < 16; ++kk) {
                        bfrag[tt][kk] = *(const half8*)(Wbig + (size_t)row * 512 + kk * 32 + q4 * 8);
                    }
                }
            }
        }
        // loop: next stage's seq-retry IS the synchronization.
    }
}

// ---------------- launch ----------------
extern "C" void kernel_launch(void* const* d_in, const int* in_sizes, int n_in,
                              void* d_out, int out_size, void* d_ws, size_t ws_size,
                              hipStream_t stream) {
    const float* z = (const float*)d_in[0];
    const float* Wih = (const float*)d_in[1];
    const float* Whh = (const float*)d_in[2];
    const float* bih = (const float*)d_in[3];
    const float* bhh = (const float*)d_in[4];
    const float* Wlast = (const float*)d_in[5];
    const float* blast = (const float*)d_in[6];
    float* out = (float*)d_out;

    char* ws = (char*)d_ws;
    unsigned short* Wbig = (unsigned short*)(ws);                // 2,621,440 B
    unsigned short* W0big = (unsigned short*)(ws + 2621440);     // 2,621,440 B
    float* biasEff = (float*)(ws + 5242880);                     // 10,240 B
    float* bias0 = (float*)(ws + 5253120);                       // 10,240 B
    unsigned int* hbuf32 = (unsigned int*)(ws + 5263360);        // 1,048,576 B

    k_weff<<<128, 256, 0, stream>>>(Wih, Whh, Wlast, Wbig);
    k_pack<<<512, 256, 0, stream>>>(z, Wih, Whh, bih, bhh, Wlast, blast, Wbig, W0big, biasEff,
                                    bias0, hbuf32);
    k_lstm<<<256, 256, 0, stream>>>(Wbig, W0big, biasEff, bias0, hbuf32, z, out);
}